// Round 1
// baseline (1931.732 us; speedup 1.0000x reference)
//
#include <hip/hip_runtime.h>

typedef __bf16 bf16_t;
typedef bf16_t bf16x8 __attribute__((ext_vector_type(8)));
typedef bf16_t bf16x4 __attribute__((ext_vector_type(4)));
typedef float floatx4 __attribute__((ext_vector_type(4)));

#define T_TOKENS 8192
#define HIDDEN 1024
#define FFN 4096
#define NE 8
#define PAIRS 16384  // T_TOKENS * TOP_K, top-2 indices are always distinct

// ---------------------------------------------------------------- gate + top2
// One wave per token: 8 dot-products of length 1024, butterfly reduce,
// lane 0 picks top-2 (strict >, ties -> lower index, matching lax.top_k).
__global__ __launch_bounds__(256) void gate_kernel(
    const float* __restrict__ x, const float* __restrict__ gw,
    const float* __restrict__ gb, int* __restrict__ top2,
    int* __restrict__ counts)
{
    const int lane = threadIdx.x & 63;
    const int wid  = threadIdx.x >> 6;
    const int t    = blockIdx.x * 4 + wid;
    const float* xr = x + (size_t)t * HIDDEN;

    float s[NE];
#pragma unroll
    for (int e = 0; e < NE; ++e) s[e] = 0.f;
    for (int k = lane; k < HIDDEN; k += 64) {
        float xv = xr[k];
        const float* g = gw + (size_t)k * NE;
#pragma unroll
        for (int e = 0; e < NE; ++e) s[e] += xv * g[e];
    }
#pragma unroll
    for (int e = 0; e < NE; ++e) {
#pragma unroll
        for (int off = 32; off > 0; off >>= 1) s[e] += __shfl_xor(s[e], off, 64);
    }
    if (lane == 0) {
        float v1 = -1e30f, v2 = -1e30f;
        int i1 = 0, i2 = 0;
#pragma unroll
        for (int e = 0; e < NE; ++e) {
            float v = s[e] + gb[e];
            if (v > v1)      { v2 = v1; i2 = i1; v1 = v; i1 = e; }
            else if (v > v2) { v2 = v;  i2 = e; }
        }
        top2[t] = i1 | (i2 << 4);
        atomicAdd(&counts[i1], 1);
        atomicAdd(&counts[i2], 1);
    }
}

// ------------------------------------------------------------- prefix offsets
__global__ void offsets_kernel(const int* __restrict__ counts,
                               int* __restrict__ offs)
{
    int acc = 0;
    for (int e = 0; e < NE; ++e) { offs[e] = acc; acc += counts[e]; }
}

// ------------------------------------------------------- scatter token lists
__global__ __launch_bounds__(256) void scatter_kernel(
    const int* __restrict__ top2, const int* __restrict__ offs,
    int* __restrict__ fill, int* __restrict__ tok)
{
    const int t = blockIdx.x * 256 + threadIdx.x;
    const int v = top2[t];
    const int e1 = v & 15, e2 = (v >> 4) & 15;
    int p1 = atomicAdd(&fill[e1], 1);
    tok[offs[e1] + p1] = t;
    int p2 = atomicAdd(&fill[e2], 1);
    tok[offs[e2] + p2] = t;
}

// --------------------------------------------------------------- GEMM1 (x@w1)
// grid: (FFN/128, 64 token tiles worst-case, 8 experts), block 256 (4 waves).
// A rows gathered via tok list; fp32 -> bf16 during LDS staging.
// Epilogue: h1[slot][f] = bf16(relu(acc + b1)).
__global__ __launch_bounds__(256) void moe_gemm1(
    const float* __restrict__ x, const float* __restrict__ w1,
    const float* __restrict__ b1, const int* __restrict__ counts,
    const int* __restrict__ offs, const int* __restrict__ tok,
    bf16_t* __restrict__ h1)
{
    const int e    = blockIdx.z;
    const int n_e  = counts[e];
    const int row0 = blockIdx.y * 128;
    if (row0 >= n_e) return;
    const int seg   = offs[e];
    const int fcol0 = blockIdx.x * 128;
    const float* W  = w1 + (size_t)e * HIDDEN * FFN;  // [H][F] row-major

    __shared__ bf16_t As[128][40];   // [token][k], +8 pad
    __shared__ bf16_t Bs[128][40];   // transposed: [f][k]
    __shared__ int s_tok[128];

    const int tid = threadIdx.x;
    if (tid < 128) {
        int idx = row0 + tid;
        s_tok[tid] = (idx < n_e) ? tok[seg + idx] : 0;
    }
    __syncthreads();

    const int lane = tid & 63, wid = tid >> 6;
    const int wm = wid & 1, wn = wid >> 1;
    const int quad = lane >> 4, lrow = lane & 15;

    floatx4 acc[4][4];
#pragma unroll
    for (int i = 0; i < 4; ++i)
#pragma unroll
        for (int j = 0; j < 4; ++j) acc[i][j] = (floatx4){0.f, 0.f, 0.f, 0.f};

    const int ar = tid >> 3, ak = (tid & 7) * 4;   // A staging map
    const int bk = tid >> 5, bf_ = (tid & 31) * 4; // B staging map

    for (int k0 = 0; k0 < HIDDEN; k0 += 32) {
#pragma unroll
        for (int p = 0; p < 4; ++p) {
            int r = p * 32 + ar;
            const float4 v = *(const float4*)(x + (size_t)s_tok[r] * HIDDEN + k0 + ak);
            bf16x4 b;
            b[0] = (bf16_t)v.x; b[1] = (bf16_t)v.y;
            b[2] = (bf16_t)v.z; b[3] = (bf16_t)v.w;
            *(bf16x4*)&As[r][ak] = b;
        }
#pragma unroll
        for (int p = 0; p < 4; ++p) {
            int kk = p * 8 + bk;
            const float4 v = *(const float4*)(W + (size_t)(k0 + kk) * FFN + fcol0 + bf_);
            Bs[bf_ + 0][kk] = (bf16_t)v.x; Bs[bf_ + 1][kk] = (bf16_t)v.y;
            Bs[bf_ + 2][kk] = (bf16_t)v.z; Bs[bf_ + 3][kk] = (bf16_t)v.w;
        }
        __syncthreads();

        bf16x8 af[4], bfr[4];
#pragma unroll
        for (int mi = 0; mi < 4; ++mi)
            af[mi] = *(const bf16x8*)&As[wm * 64 + mi * 16 + lrow][quad * 8];
#pragma unroll
        for (int ni = 0; ni < 4; ++ni)
            bfr[ni] = *(const bf16x8*)&Bs[wn * 64 + ni * 16 + lrow][quad * 8];
#pragma unroll
        for (int mi = 0; mi < 4; ++mi)
#pragma unroll
            for (int ni = 0; ni < 4; ++ni)
                acc[mi][ni] = __builtin_amdgcn_mfma_f32_16x16x32_bf16(
                    af[mi], bfr[ni], acc[mi][ni], 0, 0, 0);
        __syncthreads();
    }

#pragma unroll
    for (int ni = 0; ni < 4; ++ni) {
        const int col = wn * 64 + ni * 16 + lrow;
        const float bias = b1[(size_t)e * FFN + fcol0 + col];
#pragma unroll
        for (int mi = 0; mi < 4; ++mi) {
#pragma unroll
            for (int r = 0; r < 4; ++r) {
                int row = wm * 64 + mi * 16 + quad * 4 + r;
                if (row0 + row < n_e) {
                    float v = acc[mi][ni][r] + bias;
                    v = v > 0.f ? v : 0.f;
                    h1[(size_t)(seg + row0 + row) * FFN + fcol0 + col] = (bf16_t)v;
                }
            }
        }
    }
}

// -------------------------------------------------------------- GEMM2 (h1@w2)
// grid: (HIDDEN/128, 64 token tiles worst-case, 8 experts).
// A = h1 segment (contiguous bf16 rows). Epilogue: atomicAdd(out[t], acc+b2).
__global__ __launch_bounds__(256) void moe_gemm2(
    const bf16_t* __restrict__ h1, const float* __restrict__ w2,
    const float* __restrict__ b2, const int* __restrict__ counts,
    const int* __restrict__ offs, const int* __restrict__ tok,
    float* __restrict__ out)
{
    const int e    = blockIdx.z;
    const int n_e  = counts[e];
    const int row0 = blockIdx.y * 128;
    if (row0 >= n_e) return;
    const int seg   = offs[e];
    const int hcol0 = blockIdx.x * 128;
    const float* W  = w2 + (size_t)e * FFN * HIDDEN;  // [F][H] row-major

    __shared__ bf16_t As[128][40];
    __shared__ bf16_t Bs[128][40];  // transposed: [h][k]
    __shared__ int s_tok[128];

    const int tid = threadIdx.x;
    if (tid < 128) {
        int idx = row0 + tid;
        s_tok[tid] = (idx < n_e) ? tok[seg + idx] : 0;
    }
    __syncthreads();

    const int lane = tid & 63, wid = tid >> 6;
    const int wm = wid & 1, wn = wid >> 1;
    const int quad = lane >> 4, lrow = lane & 15;

    floatx4 acc[4][4];
#pragma unroll
    for (int i = 0; i < 4; ++i)
#pragma unroll
        for (int j = 0; j < 4; ++j) acc[i][j] = (floatx4){0.f, 0.f, 0.f, 0.f};

    const int ar = tid >> 2, ak = (tid & 3) * 8;   // A staging (bf16 source)
    const int bk = tid >> 5, bh = (tid & 31) * 4;  // B staging

    for (int k0 = 0; k0 < FFN; k0 += 32) {
#pragma unroll
        for (int p = 0; p < 2; ++p) {
            int r = p * 64 + ar;
            int srow = seg + row0 + r;
            if (srow > PAIRS - 1) srow = PAIRS - 1;  // clamp: masked in epilogue
            bf16x8 v = *(const bf16x8*)(h1 + (size_t)srow * FFN + k0 + ak);
            *(bf16x8*)&As[r][ak] = v;
        }
#pragma unroll
        for (int p = 0; p < 4; ++p) {
            int kk = p * 8 + bk;
            const float4 v = *(const float4*)(W + (size_t)(k0 + kk) * HIDDEN + hcol0 + bh);
            Bs[bh + 0][kk] = (bf16_t)v.x; Bs[bh + 1][kk] = (bf16_t)v.y;
            Bs[bh + 2][kk] = (bf16_t)v.z; Bs[bh + 3][kk] = (bf16_t)v.w;
        }
        __syncthreads();

        bf16x8 af[4], bfr[4];
#pragma unroll
        for (int mi = 0; mi < 4; ++mi)
            af[mi] = *(const bf16x8*)&As[wm * 64 + mi * 16 + lrow][quad * 8];
#pragma unroll
        for (int ni = 0; ni < 4; ++ni)
            bfr[ni] = *(const bf16x8*)&Bs[wn * 64 + ni * 16 + lrow][quad * 8];
#pragma unroll
        for (int mi = 0; mi < 4; ++mi)
#pragma unroll
            for (int ni = 0; ni < 4; ++ni)
                acc[mi][ni] = __builtin_amdgcn_mfma_f32_16x16x32_bf16(
                    af[mi], bfr[ni], acc[mi][ni], 0, 0, 0);
        __syncthreads();
    }

#pragma unroll
    for (int ni = 0; ni < 4; ++ni) {
        const int col = wn * 64 + ni * 16 + lrow;
        const float bias = b2[(size_t)e * HIDDEN + hcol0 + col];
#pragma unroll
        for (int mi = 0; mi < 4; ++mi) {
#pragma unroll
            for (int r = 0; r < 4; ++r) {
                int row = wm * 64 + mi * 16 + quad * 4 + r;
                if (row0 + row < n_e) {
                    int t = s_tok[row];
                    atomicAdd(&out[(size_t)t * HIDDEN + hcol0 + col],
                              acc[mi][ni][r] + bias);
                }
            }
        }
    }
}

// -------------------------------------------------------------------- launch
extern "C" void kernel_launch(void* const* d_in, const int* in_sizes, int n_in,
                              void* d_out, int out_size, void* d_ws, size_t ws_size,
                              hipStream_t stream)
{
    const float* x      = (const float*)d_in[0];
    const float* gate_w = (const float*)d_in[1];
    const float* gate_b = (const float*)d_in[2];
    const float* w1     = (const float*)d_in[3];
    const float* b1     = (const float*)d_in[4];
    const float* w2     = (const float*)d_in[5];
    const float* b2     = (const float*)d_in[6];
    float* out = (float*)d_out;

    // ws layout
    char* ws = (char*)d_ws;
    const size_t o_counts = 0;                 // 8 ints
    const size_t o_fill   = 32;                // 8 ints
    const size_t o_offs   = 64;                // 8 ints
    const size_t o_top2   = 128;               // T ints   (32 KB)
    const size_t o_tok    = 128 + 32768;       // PAIRS ints (64 KB)
    const size_t o_h1     = 98560;             // 256-aligned
    const size_t h1_bytes = (size_t)PAIRS * FFN * 2;  // 128 MB
    if (ws_size < o_h1 + h1_bytes) return;  // insufficient scratch: bail cleanly

    int* counts = (int*)(ws + o_counts);
    int* fill   = (int*)(ws + o_fill);
    int* offs   = (int*)(ws + o_offs);
    int* top2   = (int*)(ws + o_top2);
    int* tok    = (int*)(ws + o_tok);
    bf16_t* h1  = (bf16_t*)(ws + o_h1);

    hipMemsetAsync(ws, 0, 96, stream);                       // counts/fill/offs
    hipMemsetAsync(d_out, 0, (size_t)out_size * 4, stream);  // out accumulators

    gate_kernel<<<T_TOKENS / 4, 256, 0, stream>>>(x, gate_w, gate_b, top2, counts);
    offsets_kernel<<<1, 1, 0, stream>>>(counts, offs);
    scatter_kernel<<<T_TOKENS / 256, 256, 0, stream>>>(top2, offs, fill, tok);
    moe_gemm1<<<dim3(FFN / 128, 64, NE), 256, 0, stream>>>(x, w1, b1, counts, offs, tok, h1);
    moe_gemm2<<<dim3(HIDDEN / 128, 64, NE), 256, 0, stream>>>(h1, w2, b2, counts, offs, tok, out);
}

// Round 2
// 1159.592 us; speedup vs baseline: 1.6659x; 1.6659x over previous
//
#include <hip/hip_runtime.h>

typedef __bf16 bf16_t;
typedef bf16_t bf16x8 __attribute__((ext_vector_type(8)));
typedef bf16_t bf16x4 __attribute__((ext_vector_type(4)));
typedef float floatx4 __attribute__((ext_vector_type(4)));

#define T_TOKENS 8192
#define HIDDEN 1024
#define FFN 4096
#define NE 8
#define PAIRS 16384  // T_TOKENS * TOP_K

// async global->LDS, 16B per lane; LDS dest is wave-uniform base + lane*16
#define GLD16(gp, lp) __builtin_amdgcn_global_load_lds( \
    (const __attribute__((address_space(1))) void*)(gp), \
    (__attribute__((address_space(3))) void*)(lp), 16, 0, 0)

// ---------------------------------------------------------------- gate + top2
__global__ __launch_bounds__(256) void gate_kernel(
    const float* __restrict__ x, const float* __restrict__ gw,
    const float* __restrict__ gb, int* __restrict__ top2,
    int* __restrict__ counts)
{
    const int lane = threadIdx.x & 63;
    const int wid  = threadIdx.x >> 6;
    const int t    = blockIdx.x * 4 + wid;
    const float* xr = x + (size_t)t * HIDDEN;

    float s[NE];
#pragma unroll
    for (int e = 0; e < NE; ++e) s[e] = 0.f;
    for (int k = lane; k < HIDDEN; k += 64) {
        float xv = xr[k];
        const float* g = gw + (size_t)k * NE;
#pragma unroll
        for (int e = 0; e < NE; ++e) s[e] += xv * g[e];
    }
#pragma unroll
    for (int e = 0; e < NE; ++e) {
#pragma unroll
        for (int off = 32; off > 0; off >>= 1) s[e] += __shfl_xor(s[e], off, 64);
    }
    if (lane == 0) {
        float v1 = -1e30f, v2 = -1e30f;
        int i1 = 0, i2 = 0;
#pragma unroll
        for (int e = 0; e < NE; ++e) {
            float v = s[e] + gb[e];
            if (v > v1)      { v2 = v1; i2 = i1; v1 = v; i1 = e; }
            else if (v > v2) { v2 = v;  i2 = e; }
        }
        top2[t] = i1 | (i2 << 4);
        atomicAdd(&counts[i1], 1);
        atomicAdd(&counts[i2], 1);
    }
}

__global__ void offsets_kernel(const int* __restrict__ counts,
                               int* __restrict__ offs)
{
    int acc = 0;
    for (int e = 0; e < NE; ++e) { offs[e] = acc; acc += counts[e]; }
}

__global__ __launch_bounds__(256) void scatter_kernel(
    const int* __restrict__ top2, const int* __restrict__ offs,
    int* __restrict__ fill, int* __restrict__ tok)
{
    const int t = blockIdx.x * 256 + threadIdx.x;
    const int v = top2[t];
    const int e1 = v & 15, e2 = (v >> 4) & 15;
    int p1 = atomicAdd(&fill[e1], 1);
    tok[offs[e1] + p1] = t;
    int p2 = atomicAdd(&fill[e2], 1);
    tok[offs[e2] + p2] = t;
}

// -------------------------------------------------- fp32 -> bf16 (x)
__global__ __launch_bounds__(256) void xconv_kernel(
    const float* __restrict__ x, bf16_t* __restrict__ xb)
{
    size_t i = ((size_t)blockIdx.x * 256 + threadIdx.x) * 4;
    float4 v = *(const float4*)(x + i);
    bf16x4 b;
    b[0] = (bf16_t)v.x; b[1] = (bf16_t)v.y; b[2] = (bf16_t)v.z; b[3] = (bf16_t)v.w;
    *(bf16x4*)(xb + i) = b;
}

// ------------------------------- fp32 [E][R][C] -> bf16 [E][C][R] transpose
__global__ __launch_bounds__(256) void wtrans_kernel(
    const float* __restrict__ in, bf16_t* __restrict__ out, int R, int C)
{
    __shared__ bf16_t L[64][68];  // pad 4: 136B row stride, 8B-aligned
    const int e  = blockIdx.z;
    const int r0 = blockIdx.y * 64;
    const int c0 = blockIdx.x * 64;
    const float* ip = in + ((size_t)e * R + r0) * C + c0;
    bf16_t* op = out + ((size_t)e * C + c0) * R + r0;
    const int tid = threadIdx.x;
    const int lr = tid >> 4, lc4 = tid & 15;
#pragma unroll
    for (int p = 0; p < 4; ++p) {
        int r = p * 16 + lr;
        float4 v = *(const float4*)(ip + (size_t)r * C + lc4 * 4);
        bf16x4 b;
        b[0] = (bf16_t)v.x; b[1] = (bf16_t)v.y; b[2] = (bf16_t)v.z; b[3] = (bf16_t)v.w;
        *(bf16x4*)&L[r][lc4 * 4] = b;
    }
    __syncthreads();
#pragma unroll
    for (int p = 0; p < 4; ++p) {
        int c  = p * 16 + lr;   // output row (original col)
        int rr = lc4 * 4;       // output col group (original rows)
        bf16x4 b;
        b[0] = L[rr + 0][c]; b[1] = L[rr + 1][c];
        b[2] = L[rr + 2][c]; b[3] = L[rr + 3][c];
        *(bf16x4*)(op + (size_t)c * R + rr) = b;
    }
}

// --------------------------------------------------------- GEMM1 (m97-style)
// C[pair][f] = relu(xb[tok] @ w1t^T + b1) -> h1 bf16.  A gathered via tok.
__global__ __launch_bounds__(256) void moe_gemm1(
    const bf16_t* __restrict__ xb, const bf16_t* __restrict__ w1t,
    const float* __restrict__ b1, const int* __restrict__ counts,
    const int* __restrict__ offs, const int* __restrict__ tok,
    bf16_t* __restrict__ h1)
{
    const int e    = blockIdx.z;
    const int n_e  = counts[e];
    const int row0 = blockIdx.y * 128;
    if (row0 >= n_e) return;
    const int seg   = offs[e];
    const int fcol0 = blockIdx.x * 128;

    __shared__ bf16_t As[128 * 32];  // [row][k], unpadded (global_load_lds)
    __shared__ bf16_t Bs[128 * 32];  // [f][k]

    const int tid  = threadIdx.x;
    const int wid  = tid >> 6, lane = tid & 63;
    const int wm   = wid & 1,  wn   = wid >> 1;
    const int quad = lane >> 4, lrow = lane & 15;

    const bf16_t* pA[2]; const bf16_t* pB[2];
#pragma unroll
    for (int q = 0; q < 2; ++q) {
        int slot = q * 256 + tid;
        int arow = slot >> 2, ko = slot & 3;
        int ridx = row0 + arow; if (ridx > n_e - 1) ridx = n_e - 1;
        pA[q] = xb + (size_t)tok[seg + ridx] * HIDDEN + ko * 8;
        pB[q] = w1t + ((size_t)e * FFN + fcol0 + arow) * HIDDEN + ko * 8;
    }

    floatx4 acc[4][4];
#pragma unroll
    for (int i = 0; i < 4; ++i)
#pragma unroll
        for (int j = 0; j < 4; ++j) acc[i][j] = (floatx4){0.f, 0.f, 0.f, 0.f};

    for (int k0 = 0; k0 < HIDDEN; k0 += 32) {
#pragma unroll
        for (int q = 0; q < 2; ++q) {
            GLD16(pA[q], As + (q * 256 + wid * 64) * 8);
            GLD16(pB[q], Bs + (q * 256 + wid * 64) * 8);
            pA[q] += 32; pB[q] += 32;
        }
        __syncthreads();
        bf16x8 af[4], bfr[4];
#pragma unroll
        for (int mi = 0; mi < 4; ++mi)
            af[mi] = *(const bf16x8*)&As[(wm * 64 + mi * 16 + lrow) * 32 + quad * 8];
#pragma unroll
        for (int ni = 0; ni < 4; ++ni)
            bfr[ni] = *(const bf16x8*)&Bs[(wn * 64 + ni * 16 + lrow) * 32 + quad * 8];
#pragma unroll
        for (int mi = 0; mi < 4; ++mi)
#pragma unroll
            for (int ni = 0; ni < 4; ++ni)
                acc[mi][ni] = __builtin_amdgcn_mfma_f32_16x16x32_bf16(
                    af[mi], bfr[ni], acc[mi][ni], 0, 0, 0);
        __syncthreads();
    }

#pragma unroll
    for (int ni = 0; ni < 4; ++ni) {
        const int col = wn * 64 + ni * 16 + lrow;
        const float bias = b1[(size_t)e * FFN + fcol0 + col];
#pragma unroll
        for (int mi = 0; mi < 4; ++mi) {
#pragma unroll
            for (int r = 0; r < 4; ++r) {
                int row = wm * 64 + mi * 16 + quad * 4 + r;
                if (row0 + row < n_e) {
                    float v = acc[mi][ni][r] + bias;
                    v = v > 0.f ? v : 0.f;
                    h1[(size_t)(seg + row0 + row) * FFN + fcol0 + col] = (bf16_t)v;
                }
            }
        }
    }
}

// --------------------------------------------------------- GEMM2 (m97-style)
__global__ __launch_bounds__(256) void moe_gemm2(
    const bf16_t* __restrict__ h1, const bf16_t* __restrict__ w2t,
    const float* __restrict__ b2, const int* __restrict__ counts,
    const int* __restrict__ offs, const int* __restrict__ tok,
    float* __restrict__ out)
{
    const int e    = blockIdx.z;
    const int n_e  = counts[e];
    const int row0 = blockIdx.y * 128;
    if (row0 >= n_e) return;
    const int seg   = offs[e];
    const int hcol0 = blockIdx.x * 128;

    __shared__ bf16_t As[128 * 32];
    __shared__ bf16_t Bs[128 * 32];
    __shared__ int s_tok[128];

    const int tid  = threadIdx.x;
    const int wid  = tid >> 6, lane = tid & 63;
    const int wm   = wid & 1,  wn   = wid >> 1;
    const int quad = lane >> 4, lrow = lane & 15;

    if (tid < 128) {
        int idx = row0 + tid;
        s_tok[tid] = (idx < n_e) ? tok[seg + idx] : 0;
    }

    const bf16_t* pA[2]; const bf16_t* pB[2];
#pragma unroll
    for (int q = 0; q < 2; ++q) {
        int slot = q * 256 + tid;
        int arow = slot >> 2, ko = slot & 3;
        int ridx = row0 + arow; if (ridx > n_e - 1) ridx = n_e - 1;
        pA[q] = h1 + (size_t)(seg + ridx) * FFN + ko * 8;
        pB[q] = w2t + ((size_t)e * HIDDEN + hcol0 + arow) * FFN + ko * 8;
    }

    floatx4 acc[4][4];
#pragma unroll
    for (int i = 0; i < 4; ++i)
#pragma unroll
        for (int j = 0; j < 4; ++j) acc[i][j] = (floatx4){0.f, 0.f, 0.f, 0.f};

    for (int k0 = 0; k0 < FFN; k0 += 32) {
#pragma unroll
        for (int q = 0; q < 2; ++q) {
            GLD16(pA[q], As + (q * 256 + wid * 64) * 8);
            GLD16(pB[q], Bs + (q * 256 + wid * 64) * 8);
            pA[q] += 32; pB[q] += 32;
        }
        __syncthreads();
        bf16x8 af[4], bfr[4];
#pragma unroll
        for (int mi = 0; mi < 4; ++mi)
            af[mi] = *(const bf16x8*)&As[(wm * 64 + mi * 16 + lrow) * 32 + quad * 8];
#pragma unroll
        for (int ni = 0; ni < 4; ++ni)
            bfr[ni] = *(const bf16x8*)&Bs[(wn * 64 + ni * 16 + lrow) * 32 + quad * 8];
#pragma unroll
        for (int mi = 0; mi < 4; ++mi)
#pragma unroll
            for (int ni = 0; ni < 4; ++ni)
                acc[mi][ni] = __builtin_amdgcn_mfma_f32_16x16x32_bf16(
                    af[mi], bfr[ni], acc[mi][ni], 0, 0, 0);
        __syncthreads();
    }

#pragma unroll
    for (int ni = 0; ni < 4; ++ni) {
        const int col = wn * 64 + ni * 16 + lrow;
        const float bias = b2[(size_t)e * HIDDEN + hcol0 + col];
#pragma unroll
        for (int mi = 0; mi < 4; ++mi) {
#pragma unroll
            for (int r = 0; r < 4; ++r) {
                int row = wm * 64 + mi * 16 + quad * 4 + r;
                if (row0 + row < n_e) {
                    atomicAdd(&out[(size_t)s_tok[row] * HIDDEN + hcol0 + col],
                              acc[mi][ni][r] + bias);
                }
            }
        }
    }
}

// ===================== legacy (round-1) fallback GEMMs, fp32 weights ========
__global__ __launch_bounds__(256) void legacy_gemm1(
    const float* __restrict__ x, const float* __restrict__ w1,
    const float* __restrict__ b1, const int* __restrict__ counts,
    const int* __restrict__ offs, const int* __restrict__ tok,
    bf16_t* __restrict__ h1)
{
    const int e    = blockIdx.z;
    const int n_e  = counts[e];
    const int row0 = blockIdx.y * 128;
    if (row0 >= n_e) return;
    const int seg   = offs[e];
    const int fcol0 = blockIdx.x * 128;
    const float* W  = w1 + (size_t)e * HIDDEN * FFN;

    __shared__ bf16_t As[128][40];
    __shared__ bf16_t Bs[128][40];
    __shared__ int s_tok[128];

    const int tid = threadIdx.x;
    if (tid < 128) {
        int idx = row0 + tid;
        s_tok[tid] = (idx < n_e) ? tok[seg + idx] : 0;
    }
    __syncthreads();

    const int lane = tid & 63, wid = tid >> 6;
    const int wm = wid & 1, wn = wid >> 1;
    const int quad = lane >> 4, lrow = lane & 15;

    floatx4 acc[4][4];
#pragma unroll
    for (int i = 0; i < 4; ++i)
#pragma unroll
        for (int j = 0; j < 4; ++j) acc[i][j] = (floatx4){0.f, 0.f, 0.f, 0.f};

    const int ar = tid >> 3, ak = (tid & 7) * 4;
    const int bk = tid >> 5, bf_ = (tid & 31) * 4;

    for (int k0 = 0; k0 < HIDDEN; k0 += 32) {
#pragma unroll
        for (int p = 0; p < 4; ++p) {
            int r = p * 32 + ar;
            const float4 v = *(const float4*)(x + (size_t)s_tok[r] * HIDDEN + k0 + ak);
            bf16x4 b;
            b[0] = (bf16_t)v.x; b[1] = (bf16_t)v.y;
            b[2] = (bf16_t)v.z; b[3] = (bf16_t)v.w;
            *(bf16x4*)&As[r][ak] = b;
        }
#pragma unroll
        for (int p = 0; p < 4; ++p) {
            int kk = p * 8 + bk;
            const float4 v = *(const float4*)(W + (size_t)(k0 + kk) * FFN + fcol0 + bf_);
            Bs[bf_ + 0][kk] = (bf16_t)v.x; Bs[bf_ + 1][kk] = (bf16_t)v.y;
            Bs[bf_ + 2][kk] = (bf16_t)v.z; Bs[bf_ + 3][kk] = (bf16_t)v.w;
        }
        __syncthreads();
        bf16x8 af[4], bfr[4];
#pragma unroll
        for (int mi = 0; mi < 4; ++mi)
            af[mi] = *(const bf16x8*)&As[wm * 64 + mi * 16 + lrow][quad * 8];
#pragma unroll
        for (int ni = 0; ni < 4; ++ni)
            bfr[ni] = *(const bf16x8*)&Bs[wn * 64 + ni * 16 + lrow][quad * 8];
#pragma unroll
        for (int mi = 0; mi < 4; ++mi)
#pragma unroll
            for (int ni = 0; ni < 4; ++ni)
                acc[mi][ni] = __builtin_amdgcn_mfma_f32_16x16x32_bf16(
                    af[mi], bfr[ni], acc[mi][ni], 0, 0, 0);
        __syncthreads();
    }

#pragma unroll
    for (int ni = 0; ni < 4; ++ni) {
        const int col = wn * 64 + ni * 16 + lrow;
        const float bias = b1[(size_t)e * FFN + fcol0 + col];
#pragma unroll
        for (int mi = 0; mi < 4; ++mi) {
#pragma unroll
            for (int r = 0; r < 4; ++r) {
                int row = wm * 64 + mi * 16 + quad * 4 + r;
                if (row0 + row < n_e) {
                    float v = acc[mi][ni][r] + bias;
                    v = v > 0.f ? v : 0.f;
                    h1[(size_t)(seg + row0 + row) * FFN + fcol0 + col] = (bf16_t)v;
                }
            }
        }
    }
}

__global__ __launch_bounds__(256) void legacy_gemm2(
    const bf16_t* __restrict__ h1, const float* __restrict__ w2,
    const float* __restrict__ b2, const int* __restrict__ counts,
    const int* __restrict__ offs, const int* __restrict__ tok,
    float* __restrict__ out)
{
    const int e    = blockIdx.z;
    const int n_e  = counts[e];
    const int row0 = blockIdx.y * 128;
    if (row0 >= n_e) return;
    const int seg   = offs[e];
    const int hcol0 = blockIdx.x * 128;
    const float* W  = w2 + (size_t)e * FFN * HIDDEN;

    __shared__ bf16_t As[128][40];
    __shared__ bf16_t Bs[128][40];
    __shared__ int s_tok[128];

    const int tid = threadIdx.x;
    if (tid < 128) {
        int idx = row0 + tid;
        s_tok[tid] = (idx < n_e) ? tok[seg + idx] : 0;
    }
    __syncthreads();

    const int lane = tid & 63, wid = tid >> 6;
    const int wm = wid & 1, wn = wid >> 1;
    const int quad = lane >> 4, lrow = lane & 15;

    floatx4 acc[4][4];
#pragma unroll
    for (int i = 0; i < 4; ++i)
#pragma unroll
        for (int j = 0; j < 4; ++j) acc[i][j] = (floatx4){0.f, 0.f, 0.f, 0.f};

    const int ar = tid >> 2, ak = (tid & 3) * 8;
    const int bk = tid >> 5, bh = (tid & 31) * 4;

    for (int k0 = 0; k0 < FFN; k0 += 32) {
#pragma unroll
        for (int p = 0; p < 2; ++p) {
            int r = p * 64 + ar;
            int srow = seg + row0 + r;
            if (srow > PAIRS - 1) srow = PAIRS - 1;
            bf16x8 v = *(const bf16x8*)(h1 + (size_t)srow * FFN + k0 + ak);
            *(bf16x8*)&As[r][ak] = v;
        }
#pragma unroll
        for (int p = 0; p < 4; ++p) {
            int kk = p * 8 + bk;
            const float4 v = *(const float4*)(W + (size_t)(k0 + kk) * HIDDEN + hcol0 + bh);
            Bs[bh + 0][kk] = (bf16_t)v.x; Bs[bh + 1][kk] = (bf16_t)v.y;
            Bs[bh + 2][kk] = (bf16_t)v.z; Bs[bh + 3][kk] = (bf16_t)v.w;
        }
        __syncthreads();
        bf16x8 af[4], bfr[4];
#pragma unroll
        for (int mi = 0; mi < 4; ++mi)
            af[mi] = *(const bf16x8*)&As[wm * 64 + mi * 16 + lrow][quad * 8];
#pragma unroll
        for (int ni = 0; ni < 4; ++ni)
            bfr[ni] = *(const bf16x8*)&Bs[wn * 64 + ni * 16 + lrow][quad * 8];
#pragma unroll
        for (int mi = 0; mi < 4; ++mi)
#pragma unroll
            for (int ni = 0; ni < 4; ++ni)
                acc[mi][ni] = __builtin_amdgcn_mfma_f32_16x16x32_bf16(
                    af[mi], bfr[ni], acc[mi][ni], 0, 0, 0);
        __syncthreads();
    }

#pragma unroll
    for (int ni = 0; ni < 4; ++ni) {
        const int col = wn * 64 + ni * 16 + lrow;
        const float bias = b2[(size_t)e * HIDDEN + hcol0 + col];
#pragma unroll
        for (int mi = 0; mi < 4; ++mi) {
#pragma unroll
            for (int r = 0; r < 4; ++r) {
                int row = wm * 64 + mi * 16 + quad * 4 + r;
                if (row0 + row < n_e) {
                    atomicAdd(&out[(size_t)s_tok[row] * HIDDEN + hcol0 + col],
                              acc[mi][ni][r] + bias);
                }
            }
        }
    }
}

// -------------------------------------------------------------------- launch
extern "C" void kernel_launch(void* const* d_in, const int* in_sizes, int n_in,
                              void* d_out, int out_size, void* d_ws, size_t ws_size,
                              hipStream_t stream)
{
    const float* x      = (const float*)d_in[0];
    const float* gate_w = (const float*)d_in[1];
    const float* gate_b = (const float*)d_in[2];
    const float* w1     = (const float*)d_in[3];
    const float* b1     = (const float*)d_in[4];
    const float* w2     = (const float*)d_in[5];
    const float* b2     = (const float*)d_in[6];
    float* out = (float*)d_out;

    char* ws = (char*)d_ws;
    const size_t o_top2 = 128;
    const size_t o_tok  = 128 + 32768;
    const size_t o_base = 98560;  // 256-aligned

    int* counts = (int*)(ws + 0);
    int* fill   = (int*)(ws + 32);
    int* offs   = (int*)(ws + 64);
    int* top2   = (int*)(ws + o_top2);
    int* tok    = (int*)(ws + o_tok);

    // full path layout
    const size_t sz_xb  = (size_t)T_TOKENS * HIDDEN * 2;       // 16 MB
    const size_t sz_w1t = (size_t)NE * FFN * HIDDEN * 2;       // 64 MB
    const size_t sz_w2t = (size_t)NE * HIDDEN * FFN * 2;       // 64 MB
    const size_t sz_h1  = (size_t)PAIRS * FFN * 2;             // 128 MB
    const size_t need_full   = o_base + sz_xb + sz_w1t + sz_w2t + sz_h1;
    const size_t need_legacy = o_base + sz_h1;

    hipMemsetAsync(ws, 0, 96, stream);
    hipMemsetAsync(d_out, 0, (size_t)out_size * 4, stream);

    gate_kernel<<<T_TOKENS / 4, 256, 0, stream>>>(x, gate_w, gate_b, top2, counts);
    offsets_kernel<<<1, 1, 0, stream>>>(counts, offs);
    scatter_kernel<<<T_TOKENS / 256, 256, 0, stream>>>(top2, offs, fill, tok);

    if (ws_size >= need_full) {
        bf16_t* xb  = (bf16_t*)(ws + o_base);
        bf16_t* w1t = (bf16_t*)(ws + o_base + sz_xb);
        bf16_t* w2t = (bf16_t*)(ws + o_base + sz_xb + sz_w1t);
        bf16_t* h1  = (bf16_t*)(ws + o_base + sz_xb + sz_w1t + sz_w2t);

        xconv_kernel<<<(T_TOKENS * HIDDEN) / 1024, 256, 0, stream>>>(x, xb);
        // w1 [E][H][F] -> w1t [E][F][H]
        wtrans_kernel<<<dim3(FFN / 64, HIDDEN / 64, NE), 256, 0, stream>>>(w1, w1t, HIDDEN, FFN);
        // w2 [E][F][H] -> w2t [E][H][F]
        wtrans_kernel<<<dim3(HIDDEN / 64, FFN / 64, NE), 256, 0, stream>>>(w2, w2t, FFN, HIDDEN);

        moe_gemm1<<<dim3(FFN / 128, 32, NE), 256, 0, stream>>>(
            xb, w1t, b1, counts, offs, tok, h1);
        moe_gemm2<<<dim3(HIDDEN / 128, 32, NE), 256, 0, stream>>>(
            h1, w2t, b2, counts, offs, tok, out);
    } else if (ws_size >= need_legacy) {
        bf16_t* h1 = (bf16_t*)(ws + o_base);
        legacy_gemm1<<<dim3(FFN / 128, 64, NE), 256, 0, stream>>>(
            x, w1, b1, counts, offs, tok, h1);
        legacy_gemm2<<<dim3(HIDDEN / 128, 64, NE), 256, 0, stream>>>(
            h1, w2, b2, counts, offs, tok, out);
    }
}

// Round 3
// 1127.939 us; speedup vs baseline: 1.7126x; 1.0281x over previous
//
#include <hip/hip_runtime.h>

typedef __bf16 bf16_t;
typedef bf16_t bf16x8 __attribute__((ext_vector_type(8)));
typedef bf16_t bf16x4 __attribute__((ext_vector_type(4)));
typedef float floatx4 __attribute__((ext_vector_type(4)));

#define T_TOKENS 8192
#define HIDDEN 1024
#define FFN 4096
#define NE 8
#define PAIRS 16384   // T_TOKENS * TOP_K
#define NTILES 136    // max row tiles: PAIRS/128 + NE partials

// async global->LDS, 16B per lane; LDS dest is wave-uniform base + lane*16
#define GLD16(gp, lp) __builtin_amdgcn_global_load_lds( \
    (const __attribute__((address_space(1))) void*)(gp), \
    (__attribute__((address_space(3))) void*)(lp), 16, 0, 0)

// ---------------------------------------------------------------- gate + top2
__global__ __launch_bounds__(256) void gate_kernel(
    const float* __restrict__ x, const float* __restrict__ gw,
    const float* __restrict__ gb, unsigned* __restrict__ top2,
    int* __restrict__ counts)
{
    const int lane = threadIdx.x & 63;
    const int wid  = threadIdx.x >> 6;
    const int t    = blockIdx.x * 4 + wid;
    const float* xr = x + (size_t)t * HIDDEN;

    float s[NE];
#pragma unroll
    for (int e = 0; e < NE; ++e) s[e] = 0.f;
    for (int k = lane; k < HIDDEN; k += 64) {
        float xv = xr[k];
        const float* g = gw + (size_t)k * NE;
#pragma unroll
        for (int e = 0; e < NE; ++e) s[e] += xv * g[e];
    }
#pragma unroll
    for (int e = 0; e < NE; ++e) {
#pragma unroll
        for (int off = 32; off > 0; off >>= 1) s[e] += __shfl_xor(s[e], off, 64);
    }
    if (lane == 0) {
        float v1 = -1e30f, v2 = -1e30f;
        int i1 = 0, i2 = 0;
#pragma unroll
        for (int e = 0; e < NE; ++e) {
            float v = s[e] + gb[e];
            if (v > v1)      { v2 = v1; i2 = i1; v1 = v; i1 = e; }
            else if (v > v2) { v2 = v;  i2 = e; }
        }
        top2[t] = (unsigned)(i1 | (i2 << 4));
        atomicAdd(&counts[i1], 1);
        atomicAdd(&counts[i2], 1);
    }
}

// -------------------------------------- prefix offsets + row-tile table
// tile_info[i] = expert | (rowtile << 4);  row0 = (info>>4)*128
__global__ void offsets_kernel(const int* __restrict__ counts,
                               int* __restrict__ offs,
                               int* __restrict__ tinfo)
{
    int acc = 0, nt = 0;
    for (int e = 0; e < NE; ++e) {
        offs[e] = acc;
        int n = counts[e];
        for (int r = 0; r < n; r += 128) tinfo[nt++] = e | ((r >> 7) << 4);
        acc += n;
    }
    for (; nt < NTILES; ++nt) tinfo[nt] = (65535 << 4);  // row0 huge -> block exits
}

// ----------------------- scatter: token lists (u16) + inverse slot map (u16)
// slots16 aliases top2 (each thread reads then rewrites only its own word).
__global__ __launch_bounds__(256) void scatter_kernel(
    unsigned* __restrict__ top2_slots, const int* __restrict__ offs,
    int* __restrict__ fill, unsigned short* __restrict__ tok16)
{
    const int t = blockIdx.x * 256 + threadIdx.x;
    const unsigned v = top2_slots[t];
    const int e1 = v & 15, e2 = (v >> 4) & 15;
    int p1 = atomicAdd(&fill[e1], 1);
    int s1 = offs[e1] + p1;
    tok16[s1] = (unsigned short)t;
    int p2 = atomicAdd(&fill[e2], 1);
    int s2 = offs[e2] + p2;
    tok16[s2] = (unsigned short)t;
    top2_slots[t] = (unsigned)s1 | ((unsigned)s2 << 16);  // inverse map for combine
}

// -------------------------------------------------- fp32 -> bf16 (x)
__global__ __launch_bounds__(256) void xconv_kernel(
    const float* __restrict__ x, bf16_t* __restrict__ xb)
{
    size_t i = ((size_t)blockIdx.x * 256 + threadIdx.x) * 4;
    float4 v = *(const float4*)(x + i);
    bf16x4 b;
    b[0] = (bf16_t)v.x; b[1] = (bf16_t)v.y; b[2] = (bf16_t)v.z; b[3] = (bf16_t)v.w;
    *(bf16x4*)(xb + i) = b;
}

// ------------------------------- fp32 [E][R][C] -> bf16 [E][C][R] transpose
__global__ __launch_bounds__(256) void wtrans_kernel(
    const float* __restrict__ in, bf16_t* __restrict__ out, int R, int C)
{
    __shared__ bf16_t L[64][68];
    const int e  = blockIdx.z;
    const int r0 = blockIdx.y * 64;
    const int c0 = blockIdx.x * 64;
    const float* ip = in + ((size_t)e * R + r0) * C + c0;
    bf16_t* op = out + ((size_t)e * C + c0) * R + r0;
    const int tid = threadIdx.x;
    const int lr = tid >> 4, lc4 = tid & 15;
#pragma unroll
    for (int p = 0; p < 4; ++p) {
        int r = p * 16 + lr;
        float4 v = *(const float4*)(ip + (size_t)r * C + lc4 * 4);
        bf16x4 b;
        b[0] = (bf16_t)v.x; b[1] = (bf16_t)v.y; b[2] = (bf16_t)v.z; b[3] = (bf16_t)v.w;
        *(bf16x4*)&L[r][lc4 * 4] = b;
    }
    __syncthreads();
#pragma unroll
    for (int p = 0; p < 4; ++p) {
        int c  = p * 16 + lr;
        int rr = lc4 * 4;
        bf16x4 b;
        b[0] = L[rr + 0][c]; b[1] = L[rr + 1][c];
        b[2] = L[rr + 2][c]; b[3] = L[rr + 3][c];
        *(bf16x4*)(op + (size_t)c * R + rr) = b;
    }
}

// --------------------------------------------------------- GEMM1 (m97-style)
// h1[slot][f] = relu(xb[tok[slot]] @ w1t[e]^T + b1[e])
__global__ __launch_bounds__(256) void moe_gemm1(
    const bf16_t* __restrict__ xb, const bf16_t* __restrict__ w1t,
    const float* __restrict__ b1, const int* __restrict__ counts,
    const int* __restrict__ offs, const unsigned short* __restrict__ tok16,
    const int* __restrict__ tinfo, bf16_t* __restrict__ h1)
{
    const int info = tinfo[blockIdx.y];
    const int e    = info & 15;
    const int row0 = (info >> 4) << 7;
    const int n_e  = counts[e];
    if (row0 >= n_e) return;
    const int seg   = offs[e];
    const int fcol0 = blockIdx.x * 128;

    __shared__ bf16_t As[128 * 32];
    __shared__ bf16_t Bs[128 * 32];

    const int tid  = threadIdx.x;
    const int wid  = tid >> 6, lane = tid & 63;
    const int wm   = wid & 1,  wn   = wid >> 1;
    const int quad = lane >> 4, lrow = lane & 15;

    const bf16_t* pA[2]; const bf16_t* pB[2];
#pragma unroll
    for (int q = 0; q < 2; ++q) {
        int slot = q * 256 + tid;
        int arow = slot >> 2, ko = slot & 3;
        int ridx = row0 + arow; if (ridx > n_e - 1) ridx = n_e - 1;
        pA[q] = xb + (size_t)tok16[seg + ridx] * HIDDEN + ko * 8;
        pB[q] = w1t + ((size_t)e * FFN + fcol0 + arow) * HIDDEN + ko * 8;
    }

    floatx4 acc[4][4];
#pragma unroll
    for (int i = 0; i < 4; ++i)
#pragma unroll
        for (int j = 0; j < 4; ++j) acc[i][j] = (floatx4){0.f, 0.f, 0.f, 0.f};

    for (int k0 = 0; k0 < HIDDEN; k0 += 32) {
#pragma unroll
        for (int q = 0; q < 2; ++q) {
            GLD16(pA[q], As + (q * 256 + wid * 64) * 8);
            GLD16(pB[q], Bs + (q * 256 + wid * 64) * 8);
            pA[q] += 32; pB[q] += 32;
        }
        __syncthreads();
        bf16x8 af[4], bfr[4];
#pragma unroll
        for (int mi = 0; mi < 4; ++mi)
            af[mi] = *(const bf16x8*)&As[(wm * 64 + mi * 16 + lrow) * 32 + quad * 8];
#pragma unroll
        for (int ni = 0; ni < 4; ++ni)
            bfr[ni] = *(const bf16x8*)&Bs[(wn * 64 + ni * 16 + lrow) * 32 + quad * 8];
#pragma unroll
        for (int mi = 0; mi < 4; ++mi)
#pragma unroll
            for (int ni = 0; ni < 4; ++ni)
                acc[mi][ni] = __builtin_amdgcn_mfma_f32_16x16x32_bf16(
                    af[mi], bfr[ni], acc[mi][ni], 0, 0, 0);
        __syncthreads();
    }

#pragma unroll
    for (int ni = 0; ni < 4; ++ni) {
        const int col = wn * 64 + ni * 16 + lrow;
        const float bias = b1[(size_t)e * FFN + fcol0 + col];
#pragma unroll
        for (int mi = 0; mi < 4; ++mi) {
#pragma unroll
            for (int r = 0; r < 4; ++r) {
                int row = wm * 64 + mi * 16 + quad * 4 + r;
                if (row0 + row < n_e) {
                    float v = acc[mi][ni][r] + bias;
                    v = v > 0.f ? v : 0.f;
                    h1[(size_t)(seg + row0 + row) * FFN + fcol0 + col] = (bf16_t)v;
                }
            }
        }
    }
}

// ------------------------------------------ GEMM2: atomic-free, pair-major out
__global__ __launch_bounds__(256) void moe_gemm2(
    const bf16_t* __restrict__ h1, const bf16_t* __restrict__ w2t,
    const float* __restrict__ b2, const int* __restrict__ counts,
    const int* __restrict__ offs, const int* __restrict__ tinfo,
    float* __restrict__ out_pairs)
{
    const int info = tinfo[blockIdx.y];
    const int e    = info & 15;
    const int row0 = (info >> 4) << 7;
    const int n_e  = counts[e];
    if (row0 >= n_e) return;
    const int seg   = offs[e];
    const int hcol0 = blockIdx.x * 128;

    __shared__ bf16_t As[128 * 32];
    __shared__ bf16_t Bs[128 * 32];

    const int tid  = threadIdx.x;
    const int wid  = tid >> 6, lane = tid & 63;
    const int wm   = wid & 1,  wn   = wid >> 1;
    const int quad = lane >> 4, lrow = lane & 15;

    const bf16_t* pA[2]; const bf16_t* pB[2];
#pragma unroll
    for (int q = 0; q < 2; ++q) {
        int slot = q * 256 + tid;
        int arow = slot >> 2, ko = slot & 3;
        int ridx = row0 + arow; if (ridx > n_e - 1) ridx = n_e - 1;
        pA[q] = h1 + (size_t)(seg + ridx) * FFN + ko * 8;
        pB[q] = w2t + ((size_t)e * HIDDEN + hcol0 + arow) * FFN + ko * 8;
    }

    floatx4 acc[4][4];
#pragma unroll
    for (int i = 0; i < 4; ++i)
#pragma unroll
        for (int j = 0; j < 4; ++j) acc[i][j] = (floatx4){0.f, 0.f, 0.f, 0.f};

    for (int k0 = 0; k0 < FFN; k0 += 32) {
#pragma unroll
        for (int q = 0; q < 2; ++q) {
            GLD16(pA[q], As + (q * 256 + wid * 64) * 8);
            GLD16(pB[q], Bs + (q * 256 + wid * 64) * 8);
            pA[q] += 32; pB[q] += 32;
        }
        __syncthreads();
        bf16x8 af[4], bfr[4];
#pragma unroll
        for (int mi = 0; mi < 4; ++mi)
            af[mi] = *(const bf16x8*)&As[(wm * 64 + mi * 16 + lrow) * 32 + quad * 8];
#pragma unroll
        for (int ni = 0; ni < 4; ++ni)
            bfr[ni] = *(const bf16x8*)&Bs[(wn * 64 + ni * 16 + lrow) * 32 + quad * 8];
#pragma unroll
        for (int mi = 0; mi < 4; ++mi)
#pragma unroll
            for (int ni = 0; ni < 4; ++ni)
                acc[mi][ni] = __builtin_amdgcn_mfma_f32_16x16x32_bf16(
                    af[mi], bfr[ni], acc[mi][ni], 0, 0, 0);
        __syncthreads();
    }

#pragma unroll
    for (int ni = 0; ni < 4; ++ni) {
        const int col = wn * 64 + ni * 16 + lrow;
        const float bias = b2[(size_t)e * HIDDEN + hcol0 + col];
#pragma unroll
        for (int mi = 0; mi < 4; ++mi) {
#pragma unroll
            for (int r = 0; r < 4; ++r) {
                int row = wm * 64 + mi * 16 + quad * 4 + r;
                if (row0 + row < n_e) {
                    out_pairs[(size_t)(seg + row0 + row) * HIDDEN + hcol0 + col] =
                        acc[mi][ni][r] + bias;
                }
            }
        }
    }
}

// -------------------------- combine: out[t] = op[slot1(t)] + op[slot2(t)]
__global__ __launch_bounds__(256) void combine_kernel(
    const float* __restrict__ op, const unsigned* __restrict__ slots,
    float* __restrict__ out)
{
    const int gid = blockIdx.x * 256 + threadIdx.x;
    const int t = gid >> 8;
    const int c = (gid & 255) * 4;
    const unsigned sv = slots[t];
    const int s1 = sv & 0xffff, s2 = sv >> 16;
    float4 a = *(const float4*)(op + (size_t)s1 * HIDDEN + c);
    float4 b = *(const float4*)(op + (size_t)s2 * HIDDEN + c);
    float4 o;
    o.x = a.x + b.x; o.y = a.y + b.y; o.z = a.z + b.z; o.w = a.w + b.w;
    *(float4*)(out + (size_t)t * HIDDEN + c) = o;
}

// -------------------------------------------------------------------- launch
extern "C" void kernel_launch(void* const* d_in, const int* in_sizes, int n_in,
                              void* d_out, int out_size, void* d_ws, size_t ws_size,
                              hipStream_t stream)
{
    const float* x      = (const float*)d_in[0];
    const float* gate_w = (const float*)d_in[1];
    const float* gate_b = (const float*)d_in[2];
    const float* w1     = (const float*)d_in[3];
    const float* b1     = (const float*)d_in[4];
    const float* w2     = (const float*)d_in[5];
    const float* b2     = (const float*)d_in[6];
    float* out = (float*)d_out;

    char* ws = (char*)d_ws;
    // header (all within the round-2-proven 98560-byte budget)
    int*      counts = (int*)(ws + 0);       // 32 B
    int*      fill   = (int*)(ws + 32);      // 32 B
    int*      offs   = (int*)(ws + 64);      // 32 B
    int*      tinfo  = (int*)(ws + 96);      // 136*4 = 544 B -> 640
    unsigned* top2   = (unsigned*)(ws + 640);        // 32 KB (union w/ slot map)
    unsigned short* tok16 = (unsigned short*)(ws + 640 + 32768);  // 32 KB
    const size_t o_base = 98560;

    const size_t sz_xb  = (size_t)T_TOKENS * HIDDEN * 2;   // 16 MB
    const size_t sz_w1t = (size_t)NE * FFN * HIDDEN * 2;   // 64 MB
    const size_t sz_w2t = (size_t)NE * HIDDEN * FFN * 2;   // 64 MB
    const size_t sz_h1  = (size_t)PAIRS * FFN * 2;         // 128 MB
    const size_t need = o_base + sz_xb + sz_w1t + sz_w2t + sz_h1;  // == round-2 need_full
    if (ws_size < need) return;

    bf16_t* xb  = (bf16_t*)(ws + o_base);
    bf16_t* w1t = (bf16_t*)(ws + o_base + sz_xb);
    bf16_t* w2t = (bf16_t*)(ws + o_base + sz_xb + sz_w1t);
    bf16_t* h1  = (bf16_t*)(ws + o_base + sz_xb + sz_w1t + sz_w2t);
    float* out_pairs = (float*)w1t;  // 64 MB, dead after gemm1 (PAIRS*H*4 = 64 MB)

    hipMemsetAsync(ws, 0, 96, stream);  // counts/fill/offs

    gate_kernel<<<T_TOKENS / 4, 256, 0, stream>>>(x, gate_w, gate_b, top2, counts);
    offsets_kernel<<<1, 1, 0, stream>>>(counts, offs, tinfo);
    scatter_kernel<<<T_TOKENS / 256, 256, 0, stream>>>(top2, offs, fill, tok16);

    xconv_kernel<<<(T_TOKENS * HIDDEN) / 1024, 256, 0, stream>>>(x, xb);
    wtrans_kernel<<<dim3(FFN / 64, HIDDEN / 64, NE), 256, 0, stream>>>(w1, w1t, HIDDEN, FFN);
    wtrans_kernel<<<dim3(HIDDEN / 64, FFN / 64, NE), 256, 0, stream>>>(w2, w2t, FFN, HIDDEN);

    moe_gemm1<<<dim3(FFN / 128, NTILES), 256, 0, stream>>>(
        xb, w1t, b1, counts, offs, tok16, tinfo, h1);
    moe_gemm2<<<dim3(HIDDEN / 128, NTILES), 256, 0, stream>>>(
        h1, w2t, b2, counts, offs, tinfo, out_pairs);
    combine_kernel<<<(T_TOKENS * HIDDEN / 4) / 256, 256, 0, stream>>>(
        out_pairs, top2, out);
}